// Round 1
// baseline (303.859 us; speedup 1.0000x reference)
//
#include <hip/hip_runtime.h>
#include <hip/hip_bf16.h>
#include <math.h>

#define W_    384
#define H_    384
#define HW_   (384*384)
#define C_    256
#define NOBJ  16
#define NP    128
#define N2    2048
#define IMGW  384.0f
#define IMGH  384.0f
#define NCH   32          // n-chunks of 64 in the sim/dist kernel

// ---------------------------------------------------------------------------
// Kernel 1: transpose feats [C,H,W] f32  ->  featsT [H*W, C] bf16
// LDS-tiled 64ch x 64pos; coalesced read along HW, coalesced write along C.
// ---------------------------------------------------------------------------
__global__ __launch_bounds__(256) void k_transpose(const float* __restrict__ feats,
                                                   unsigned short* __restrict__ ftT) {
    __shared__ float tile[64][65];           // +1 pad: conflict-free both phases
    int b     = blockIdx.x;
    int pbase = (b % (HW_ / 64)) * 64;
    int cbase = (b / (HW_ / 64)) * 64;
    int lane  = threadIdx.x & 63;
    int grp   = threadIdx.x >> 6;

    #pragma unroll
    for (int r = 0; r < 16; ++r) {
        int c = r * 4 + grp;
        tile[c][lane] = feats[(size_t)(cbase + c) * HW_ + pbase + lane];
    }
    __syncthreads();
    #pragma unroll
    for (int r = 0; r < 16; ++r) {
        int p = r * 4 + grp;
        float v = tile[lane][p];
        unsigned int u = __float_as_uint(v);
        u += 0x7fffu + ((u >> 16) & 1u);     // RNE f32 -> bf16
        ftT[(size_t)(pbase + p) * C_ + cbase + lane] = (unsigned short)(u >> 16);
    }
}

// ---------------------------------------------------------------------------
// Kernel 2: bilinear sample from featsT [H*W, C] bf16.
// One 64-lane wave per point; each lane handles 4 contiguous channels.
// ---------------------------------------------------------------------------
__global__ __launch_bounds__(256) void k_sample(const float* __restrict__ pts, int npts,
                                                const unsigned short* __restrict__ ftT,
                                                float* __restrict__ out) {
    int point = blockIdx.x * 4 + (threadIdx.x >> 6);
    if (point >= npts) return;
    int lane  = threadIdx.x & 63;
    int cb    = lane * 4;

    float px = pts[point * 2 + 0];
    float py = pts[point * 2 + 1];
    float x  = px * ((float)W_ / IMGW) - 0.5f;   // grid_sample, align_corners=False
    float y  = py * ((float)H_ / IMGH) - 0.5f;
    float x0 = floorf(x), y0 = floorf(y);
    int ix0 = (int)x0, iy0 = (int)y0;
    float fx = x - x0, fy = y - y0;

    float a0 = 0.f, a1 = 0.f, a2 = 0.f, a3 = 0.f;
    #pragma unroll
    for (int dy = 0; dy < 2; ++dy) {
        #pragma unroll
        for (int dx = 0; dx < 2; ++dx) {
            int ix = ix0 + dx, iy = iy0 + dy;
            float w = (dx ? fx : 1.f - fx) * (dy ? fy : 1.f - fy);
            if (ix >= 0 && ix < W_ && iy >= 0 && iy < H_) {   // wave-uniform branch
                const ushort4 t = *(const ushort4*)(ftT + ((size_t)(iy * W_ + ix) * C_ + cb));
                a0 += w * __uint_as_float((unsigned)t.x << 16);
                a1 += w * __uint_as_float((unsigned)t.y << 16);
                a2 += w * __uint_as_float((unsigned)t.z << 16);
                a3 += w * __uint_as_float((unsigned)t.w << 16);
            }
        }
    }
    float4 o; o.x = a0; o.y = a1; o.z = a2; o.w = a3;
    *(float4*)(out + (size_t)point * C_ + cb) = o;
}

// Fallback sampler (no transpose): gathers straight from [C,H,W] f32.
__global__ __launch_bounds__(256) void k_sample_direct(const float* __restrict__ pts, int npts,
                                                       const float* __restrict__ feats,
                                                       float* __restrict__ out) {
    int point = blockIdx.x * 4 + (threadIdx.x >> 6);
    if (point >= npts) return;
    int lane  = threadIdx.x & 63;
    int cb    = lane * 4;

    float px = pts[point * 2 + 0];
    float py = pts[point * 2 + 1];
    float x  = px * ((float)W_ / IMGW) - 0.5f;
    float y  = py * ((float)H_ / IMGH) - 0.5f;
    float x0 = floorf(x), y0 = floorf(y);
    int ix0 = (int)x0, iy0 = (int)y0;
    float fx = x - x0, fy = y - y0;

    float acc[4] = {0.f, 0.f, 0.f, 0.f};
    #pragma unroll
    for (int dy = 0; dy < 2; ++dy) {
        #pragma unroll
        for (int dx = 0; dx < 2; ++dx) {
            int ix = ix0 + dx, iy = iy0 + dy;
            float w = (dx ? fx : 1.f - fx) * (dy ? fy : 1.f - fy);
            if (ix >= 0 && ix < W_ && iy >= 0 && iy < H_) {
                int base = iy * W_ + ix;
                #pragma unroll
                for (int u = 0; u < 4; ++u)
                    acc[u] += w * feats[(size_t)(cb + u) * HW_ + base];
            }
        }
    }
    float4 o; o.x = acc[0]; o.y = acc[1]; o.z = acc[2]; o.w = acc[3];
    *(float4*)(out + (size_t)point * C_ + cb) = o;
}

// ---------------------------------------------------------------------------
// Kernel 3: per (object, 64-p tile, 64-n chunk): fp32 sign-dot GEMM + masked
// distance min/sum/cnt partials. 256 threads, 4x4 acc/thread, KT=16.
// ---------------------------------------------------------------------------
__global__ __launch_bounds__(256) void k_simdist(const float* __restrict__ f1,
                                                 const float* __restrict__ f2,
                                                 const float* __restrict__ ps1,
                                                 const float* __restrict__ ps2,
                                                 float* __restrict__ pmin,
                                                 float* __restrict__ psum,
                                                 float* __restrict__ pcnt) {
    __shared__ __align__(16) float As[16][64];
    __shared__ __align__(16) float Bs[16][64];
    __shared__ float s1x[64], s1y[64], s2x[64], s2y[64];

    int b  = blockIdx.x;          // 1024 blocks: o(16) x pc(2) x nc(32)
    int o  = b >> 6;
    int pc = (b >> 5) & 1;
    int nc = b & 31;
    int pbase = pc * 64, nbase = nc * 64;
    int t  = threadIdx.x;

    if (t < 64) {
        const float* q = ps1 + (size_t)(o * NP + pbase + t) * 2;
        s1x[t] = q[0]; s1y[t] = q[1];
    } else if (t < 128) {
        int n = t - 64;
        const float* q = ps2 + (size_t)(o * N2 + nbase + n) * 2;
        s2x[n] = q[0]; s2y[n] = q[1];
    }

    int tx = t & 15, ty = t >> 4;
    float acc[4][4] = {};

    int lrow = t >> 2;            // 0..63
    int lk   = (t & 3) * 4;       // 0,4,8,12
    const float* aptr = f1 + ((size_t)(o * NP + pbase + lrow) * C_ + lk);
    const float* bptr = f2 + ((size_t)(o * N2 + nbase + lrow) * C_ + lk);

    for (int kb = 0; kb < C_; kb += 16) {
        float4 av = *(const float4*)(aptr + kb);
        float4 bv = *(const float4*)(bptr + kb);
        __syncthreads();
        As[lk + 0][lrow] = av.x; As[lk + 1][lrow] = av.y;
        As[lk + 2][lrow] = av.z; As[lk + 3][lrow] = av.w;
        Bs[lk + 0][lrow] = bv.x; Bs[lk + 1][lrow] = bv.y;
        Bs[lk + 2][lrow] = bv.z; Bs[lk + 3][lrow] = bv.w;
        __syncthreads();
        #pragma unroll
        for (int kk = 0; kk < 16; ++kk) {
            float4 a4 = *(const float4*)&As[kk][ty * 4];
            float4 b4 = *(const float4*)&Bs[kk][tx * 4];
            acc[0][0] += a4.x * b4.x; acc[0][1] += a4.x * b4.y;
            acc[0][2] += a4.x * b4.z; acc[0][3] += a4.x * b4.w;
            acc[1][0] += a4.y * b4.x; acc[1][1] += a4.y * b4.y;
            acc[1][2] += a4.y * b4.z; acc[1][3] += a4.y * b4.w;
            acc[2][0] += a4.z * b4.x; acc[2][1] += a4.z * b4.y;
            acc[2][2] += a4.z * b4.z; acc[2][3] += a4.z * b4.w;
            acc[3][0] += a4.w * b4.x; acc[3][1] += a4.w * b4.y;
            acc[3][2] += a4.w * b4.z; acc[3][3] += a4.w * b4.w;
        }
    }

    // Epilogue: masked distance stats per p-row, reduce over the 16 tx lanes.
    #pragma unroll
    for (int i = 0; i < 4; ++i) {
        int pl = ty * 4 + i;
        float px = s1x[pl], py = s1y[pl];
        float mn = INFINITY, sm = 0.f, ct = 0.f;
        #pragma unroll
        for (int j = 0; j < 4; ++j) {
            int nl = tx * 4 + j;
            if (acc[i][j] >= 0.f) {          // sims >= 0  <=>  dot >= 0
                float dx = px - s2x[nl], dy = py - s2y[nl];
                float d  = sqrtf(dx * dx + dy * dy);
                mn = fminf(mn, d); sm += d; ct += 1.f;
            }
        }
        #pragma unroll
        for (int off = 1; off < 16; off <<= 1) {
            mn = fminf(mn, __shfl_xor(mn, off, 16));
            sm += __shfl_xor(sm, off, 16);
            ct += __shfl_xor(ct, off, 16);
        }
        if (tx == 0) {
            int idx = (o * NCH + nc) * NP + pbase + pl;
            pmin[idx] = mn; psum[idx] = sm; pcnt[idx] = ct;
        }
    }
}

// ---------------------------------------------------------------------------
// Kernel 4: combine chunk partials -> scalar loss.
// ---------------------------------------------------------------------------
__global__ __launch_bounds__(256) void k_final(const float* __restrict__ pmin,
                                               const float* __restrict__ psum,
                                               const float* __restrict__ pcnt,
                                               float* __restrict__ out) {
    int t = threadIdx.x;
    float tot = 0.f;
    for (int pair = t; pair < NOBJ * NP; pair += 256) {
        int o = pair >> 7, p = pair & 127;
        float mn = INFINITY, sm = 0.f, ct = 0.f;
        for (int ch = 0; ch < NCH; ++ch) {
            int idx = (o * NCH + ch) * NP + p;
            mn = fminf(mn, pmin[idx]);
            sm += psum[idx];
            ct += pcnt[idx];
        }
        if (ct > 0.f) tot += 0.5f * (mn + sm / ct);
    }
    #pragma unroll
    for (int off = 32; off; off >>= 1) tot += __shfl_xor(tot, off, 64);
    __shared__ float wsum[4];
    if ((t & 63) == 0) wsum[t >> 6] = tot;
    __syncthreads();
    if (t == 0)
        out[0] = (wsum[0] + wsum[1] + wsum[2] + wsum[3]) * (1.0f / (NOBJ * NP));
}

// ---------------------------------------------------------------------------
extern "C" void kernel_launch(void* const* d_in, const int* in_sizes, int n_in,
                              void* d_out, int out_size, void* d_ws, size_t ws_size,
                              hipStream_t stream) {
    const float* ps1   = (const float*)d_in[0];  // [16,128,2]
    const float* ps2   = (const float*)d_in[1];  // [16,2048,2]
    const float* feats = (const float*)d_in[2];  // [1,256,384,384]
    const float* kpts  = (const float*)d_in[3];  // [2048,2]
    float* out = (float*)d_out;

    const size_t sz_ftT  = (size_t)HW_ * C_ * sizeof(unsigned short); // 75,497,472
    const size_t sz_f1   = (size_t)NOBJ * NP * C_ * sizeof(float);    //  2,097,152
    const size_t sz_f2   = (size_t)NOBJ * N2 * C_ * sizeof(float);    // 33,554,432
    const size_t sz_part = (size_t)NOBJ * NCH * NP * sizeof(float);   //    262,144
    const size_t need_full = sz_ftT + sz_f1 + sz_f2 + 3 * sz_part;

    char* ws = (char*)d_ws;
    if (ws_size >= need_full) {
        unsigned short* ftT = (unsigned short*)ws;
        float* f1   = (float*)(ws + sz_ftT);
        float* f2   = (float*)(ws + sz_ftT + sz_f1);
        float* pmin = (float*)(ws + sz_ftT + sz_f1 + sz_f2);
        float* psum = (float*)(ws + sz_ftT + sz_f1 + sz_f2 + sz_part);
        float* pcnt = (float*)(ws + sz_ftT + sz_f1 + sz_f2 + 2 * sz_part);

        k_transpose<<<(HW_ / 64) * (C_ / 64), 256, 0, stream>>>(feats, ftT);
        k_sample<<<(NOBJ * NP) / 4, 256, 0, stream>>>(kpts, NOBJ * NP, ftT, f1);
        k_sample<<<(NOBJ * N2) / 4, 256, 0, stream>>>(ps2, NOBJ * N2, ftT, f2);
        k_simdist<<<NOBJ * 2 * NCH, 256, 0, stream>>>(f1, f2, ps1, ps2, pmin, psum, pcnt);
        k_final<<<1, 256, 0, stream>>>(pmin, psum, pcnt, out);
    } else {
        // Fallback: no transposed copy; gather straight from [C,H,W].
        float* f1   = (float*)ws;
        float* f2   = (float*)(ws + sz_f1);
        float* pmin = (float*)(ws + sz_f1 + sz_f2);
        float* psum = (float*)(ws + sz_f1 + sz_f2 + sz_part);
        float* pcnt = (float*)(ws + sz_f1 + sz_f2 + 2 * sz_part);

        k_sample_direct<<<(NOBJ * NP) / 4, 256, 0, stream>>>(kpts, NOBJ * NP, feats, f1);
        k_sample_direct<<<(NOBJ * N2) / 4, 256, 0, stream>>>(ps2, NOBJ * N2, feats, f2);
        k_simdist<<<NOBJ * 2 * NCH, 256, 0, stream>>>(f1, f2, ps1, ps2, pmin, psum, pcnt);
        k_final<<<1, 256, 0, stream>>>(pmin, psum, pcnt, out);
    }
}

// Round 2
// 277.670 us; speedup vs baseline: 1.0943x; 1.0943x over previous
//
#include <hip/hip_runtime.h>
#include <hip/hip_bf16.h>
#include <math.h>

#define W_    384
#define H_    384
#define HW_   (384*384)
#define C_    256
#define NOBJ  16
#define NP    128
#define N2    2048
#define NF1   (NOBJ*NP)            // 2048 key points
#define NPTS  (NOBJ*NP + NOBJ*N2)  // 34816 total sampled points
#define NG    16                   // n-groups of 128 in simdist
#define NT    8                    // 16-wide n-tiles per group

typedef __attribute__((ext_vector_type(8))) short short8;
typedef __attribute__((ext_vector_type(4))) float f32x4;

// ---------------------------------------------------------------------------
// Kernel 1: transpose feats [C,H,W] f32 -> ftT [H*W, C] bf16.
// 64ch x 64pos LDS tile; coalesced read along HW, coalesced write along C.
// HBM-bound: 151 MB read + 75.5 MB write.
// ---------------------------------------------------------------------------
__global__ __launch_bounds__(256) void k_transpose(const float* __restrict__ feats,
                                                   unsigned short* __restrict__ ftT) {
    __shared__ float tile[64][65];
    int b     = blockIdx.x;
    int pbase = (b % (HW_ / 64)) * 64;
    int cbase = (b / (HW_ / 64)) * 64;
    int lane  = threadIdx.x & 63;
    int grp   = threadIdx.x >> 6;

    #pragma unroll
    for (int r = 0; r < 16; ++r) {
        int c = r * 4 + grp;
        tile[c][lane] = feats[(size_t)(cbase + c) * HW_ + pbase + lane];
    }
    __syncthreads();
    #pragma unroll
    for (int r = 0; r < 16; ++r) {
        int p = r * 4 + grp;
        unsigned int u = __float_as_uint(tile[lane][p]);
        u += 0x7fffu + ((u >> 16) & 1u);            // RNE f32->bf16
        ftT[(size_t)(pbase + p) * C_ + cbase + lane] = (unsigned short)(u >> 16);
    }
}

// ---------------------------------------------------------------------------
// Kernel 2: bilinear sample -> f12 [NPTS, C] bf16 (rows 0..2047 = f1 from
// key_points, rows 2048.. = f2 from point_set_2). One wave per point, 4
// channels per lane; taps are contiguous 512 B rows of ftT.
// ---------------------------------------------------------------------------
__global__ __launch_bounds__(256) void k_sample(const float* __restrict__ kpts,
                                                const float* __restrict__ ps2,
                                                const unsigned short* __restrict__ ftT,
                                                unsigned short* __restrict__ f12) {
    int point = blockIdx.x * 4 + (threadIdx.x >> 6);
    int lane  = threadIdx.x & 63;
    int cb    = lane * 4;

    const float* src = (point < NF1) ? (kpts + (size_t)point * 2)
                                     : (ps2 + (size_t)(point - NF1) * 2);
    float px = src[0], py = src[1];
    // img_size == (W,H) so normalization cancels: x = px - 0.5 (align_corners=F)
    float x  = px - 0.5f;
    float y  = py - 0.5f;
    float x0 = floorf(x), y0 = floorf(y);
    int ix0 = (int)x0, iy0 = (int)y0;
    float fx = x - x0, fy = y - y0;

    float a0 = 0.f, a1 = 0.f, a2 = 0.f, a3 = 0.f;
    #pragma unroll
    for (int dy = 0; dy < 2; ++dy) {
        #pragma unroll
        for (int dx = 0; dx < 2; ++dx) {
            int ix = ix0 + dx, iy = iy0 + dy;
            float w = (dx ? fx : 1.f - fx) * (dy ? fy : 1.f - fy);
            if (ix >= 0 && ix < W_ && iy >= 0 && iy < H_) {   // wave-uniform
                const ushort4 t = *(const ushort4*)(ftT + ((size_t)(iy * W_ + ix) * C_ + cb));
                a0 += w * __uint_as_float((unsigned)t.x << 16);
                a1 += w * __uint_as_float((unsigned)t.y << 16);
                a2 += w * __uint_as_float((unsigned)t.z << 16);
                a3 += w * __uint_as_float((unsigned)t.w << 16);
            }
        }
    }
    ushort4 o;
    unsigned u;
    u = __float_as_uint(a0); u += 0x7fffu + ((u >> 16) & 1u); o.x = (unsigned short)(u >> 16);
    u = __float_as_uint(a1); u += 0x7fffu + ((u >> 16) & 1u); o.y = (unsigned short)(u >> 16);
    u = __float_as_uint(a2); u += 0x7fffu + ((u >> 16) & 1u); o.z = (unsigned short)(u >> 16);
    u = __float_as_uint(a3); u += 0x7fffu + ((u >> 16) & 1u); o.w = (unsigned short)(u >> 16);
    *(ushort4*)(f12 + (size_t)point * C_ + cb) = o;
}

// Fallback sampler (no transposed copy): gathers straight from [C,H,W] f32.
__global__ __launch_bounds__(256) void k_sample_direct(const float* __restrict__ kpts,
                                                       const float* __restrict__ ps2,
                                                       const float* __restrict__ feats,
                                                       unsigned short* __restrict__ f12) {
    int point = blockIdx.x * 4 + (threadIdx.x >> 6);
    int lane  = threadIdx.x & 63;
    int cb    = lane * 4;

    const float* src = (point < NF1) ? (kpts + (size_t)point * 2)
                                     : (ps2 + (size_t)(point - NF1) * 2);
    float px = src[0], py = src[1];
    float x  = px - 0.5f, y = py - 0.5f;
    float x0 = floorf(x), y0 = floorf(y);
    int ix0 = (int)x0, iy0 = (int)y0;
    float fx = x - x0, fy = y - y0;

    float acc[4] = {0.f, 0.f, 0.f, 0.f};
    #pragma unroll
    for (int dy = 0; dy < 2; ++dy) {
        #pragma unroll
        for (int dx = 0; dx < 2; ++dx) {
            int ix = ix0 + dx, iy = iy0 + dy;
            float w = (dx ? fx : 1.f - fx) * (dy ? fy : 1.f - fy);
            if (ix >= 0 && ix < W_ && iy >= 0 && iy < H_) {
                int base = iy * W_ + ix;
                #pragma unroll
                for (int u = 0; u < 4; ++u)
                    acc[u] += w * feats[(size_t)(cb + u) * HW_ + base];
            }
        }
    }
    ushort4 o;
    unsigned u;
    u = __float_as_uint(acc[0]); u += 0x7fffu + ((u >> 16) & 1u); o.x = (unsigned short)(u >> 16);
    u = __float_as_uint(acc[1]); u += 0x7fffu + ((u >> 16) & 1u); o.y = (unsigned short)(u >> 16);
    u = __float_as_uint(acc[2]); u += 0x7fffu + ((u >> 16) & 1u); o.z = (unsigned short)(u >> 16);
    u = __float_as_uint(acc[3]); u += 0x7fffu + ((u >> 16) & 1u); o.w = (unsigned short)(u >> 16);
    *(ushort4*)(f12 + (size_t)point * C_ + cb) = o;
}

// ---------------------------------------------------------------------------
// Kernel 3: bf16 MFMA sign-dot + masked distance stats.
// One wave per (o, 16-p tile, 128-n group). A-frags (full K=256) held in
// 32 VGPRs; loops 8 n-tiles of 16, loading B-frags straight from global
// (no LDS). mask = (dot >= 0); per-p min/sum/cnt accumulated per-lane,
// one 16-lane shuffle reduce at the end.
// MFMA C/D layout (m89): col = lane&15, row = (lane>>4)*4 + reg.
// A/B frag (m89): m(or n) = lane&15, k = (lane>>4)*8 + j.
// ---------------------------------------------------------------------------
__global__ __launch_bounds__(256) void k_simdist(const unsigned short* __restrict__ f12,
                                                 const float* __restrict__ ps1,
                                                 const float* __restrict__ ps2,
                                                 float* __restrict__ pmin,
                                                 float* __restrict__ psum,
                                                 float* __restrict__ pcnt) {
    int wid  = blockIdx.x * 4 + (threadIdx.x >> 6);   // 0..2047
    int lane = threadIdx.x & 63;
    int ng = wid & 15;
    int pt = (wid >> 4) & 7;
    int o  = wid >> 7;
    int quad = lane >> 4, col = lane & 15;

    // A fragments: f1 row = o*NP + pt*16 + col, 8 k-blocks of 32.
    const short* f12s = (const short*)f12;
    const short8* aptr =
        (const short8*)(f12s + ((size_t)(o * NP + pt * 16 + col) * C_ + quad * 8));
    short8 a[8];
    #pragma unroll
    for (int kb = 0; kb < 8; ++kb) a[kb] = aptr[kb * 4];   // +32 bf16 per block

    const float2* ps1v = (const float2*)ps1;
    const float2* ps2v = (const float2*)ps2;
    float pxr[4], pyr[4];
    #pragma unroll
    for (int r = 0; r < 4; ++r) {
        float2 pc = ps1v[o * NP + pt * 16 + quad * 4 + r];
        pxr[r] = pc.x; pyr[r] = pc.y;
    }

    float mn[4] = {INFINITY, INFINITY, INFINITY, INFINITY};
    float sm[4] = {0.f, 0.f, 0.f, 0.f};
    float ct[4] = {0.f, 0.f, 0.f, 0.f};

    for (int t = 0; t < NT; ++t) {
        int nbase = ng * 128 + t * 16;
        const short8* bptr =
            (const short8*)(f12s + ((size_t)(NF1 + o * N2 + nbase + col) * C_ + quad * 8));
        f32x4 acc = {0.f, 0.f, 0.f, 0.f};
        #pragma unroll
        for (int kb = 0; kb < 8; ++kb)
            acc = __builtin_amdgcn_mfma_f32_16x16x32_bf16(a[kb], bptr[kb * 4], acc, 0, 0, 0);

        float2 nc = ps2v[o * N2 + nbase + col];   // this lane's n-column coords
        #pragma unroll
        for (int r = 0; r < 4; ++r) {
            if (acc[r] >= 0.f) {                  // sims >= 0  <=>  dot >= 0
                float dx = pxr[r] - nc.x, dy = pyr[r] - nc.y;
                float d  = sqrtf(dx * dx + dy * dy);
                mn[r] = fminf(mn[r], d); sm[r] += d; ct[r] += 1.f;
            }
        }
    }

    #pragma unroll
    for (int r = 0; r < 4; ++r) {
        #pragma unroll
        for (int off = 1; off < 16; off <<= 1) {
            mn[r] = fminf(mn[r], __shfl_xor(mn[r], off, 16));
            sm[r] += __shfl_xor(sm[r], off, 16);
            ct[r] += __shfl_xor(ct[r], off, 16);
        }
    }
    if (col == 0) {
        #pragma unroll
        for (int r = 0; r < 4; ++r) {
            int p   = pt * 16 + quad * 4 + r;
            int idx = (o * NG + ng) * NP + p;
            pmin[idx] = mn[r]; psum[idx] = sm[r]; pcnt[idx] = ct[r];
        }
    }
}

// ---------------------------------------------------------------------------
// Kernel 4: combine group partials -> scalar loss.
// ---------------------------------------------------------------------------
__global__ __launch_bounds__(256) void k_final(const float* __restrict__ pmin,
                                               const float* __restrict__ psum,
                                               const float* __restrict__ pcnt,
                                               float* __restrict__ out) {
    int t = threadIdx.x;
    float tot = 0.f;
    for (int pair = t; pair < NOBJ * NP; pair += 256) {
        int o = pair >> 7, p = pair & 127;
        float mn = INFINITY, sm = 0.f, ct = 0.f;
        for (int g = 0; g < NG; ++g) {
            int idx = (o * NG + g) * NP + p;
            mn = fminf(mn, pmin[idx]);
            sm += psum[idx];
            ct += pcnt[idx];
        }
        if (ct > 0.f) tot += 0.5f * (mn + sm / ct);
    }
    #pragma unroll
    for (int off = 32; off; off >>= 1) tot += __shfl_xor(tot, off, 64);
    __shared__ float wsum[4];
    if ((t & 63) == 0) wsum[t >> 6] = tot;
    __syncthreads();
    if (t == 0)
        out[0] = (wsum[0] + wsum[1] + wsum[2] + wsum[3]) * (1.0f / (NOBJ * NP));
}

// ---------------------------------------------------------------------------
extern "C" void kernel_launch(void* const* d_in, const int* in_sizes, int n_in,
                              void* d_out, int out_size, void* d_ws, size_t ws_size,
                              hipStream_t stream) {
    const float* ps1   = (const float*)d_in[0];  // [16,128,2]
    const float* ps2   = (const float*)d_in[1];  // [16,2048,2]
    const float* feats = (const float*)d_in[2];  // [1,256,384,384]
    const float* kpts  = (const float*)d_in[3];  // [2048,2]
    float* out = (float*)d_out;

    const size_t sz_ftT  = (size_t)HW_ * C_ * sizeof(unsigned short);   // 75,497,472
    const size_t sz_f12  = (size_t)NPTS * C_ * sizeof(unsigned short);  // 17,825,792
    const size_t sz_part = (size_t)NOBJ * NG * NP * sizeof(float);      //    131,072

    char* ws = (char*)d_ws;
    if (ws_size >= sz_ftT + sz_f12 + 3 * sz_part) {
        unsigned short* ftT = (unsigned short*)ws;
        unsigned short* f12 = (unsigned short*)(ws + sz_ftT);
        float* pmin = (float*)(ws + sz_ftT + sz_f12);
        float* psum = (float*)(ws + sz_ftT + sz_f12 + sz_part);
        float* pcnt = (float*)(ws + sz_ftT + sz_f12 + 2 * sz_part);

        k_transpose<<<(HW_ / 64) * (C_ / 64), 256, 0, stream>>>(feats, ftT);
        k_sample<<<NPTS / 4, 256, 0, stream>>>(kpts, ps2, ftT, f12);
        k_simdist<<<NOBJ * 8 * NG / 4, 256, 0, stream>>>(f12, ps1, ps2, pmin, psum, pcnt);
        k_final<<<1, 256, 0, stream>>>(pmin, psum, pcnt, out);
    } else {
        // Fallback: no transposed feature copy (uncoalesced gathers, but correct).
        unsigned short* f12 = (unsigned short*)ws;
        float* pmin = (float*)(ws + sz_f12);
        float* psum = (float*)(ws + sz_f12 + sz_part);
        float* pcnt = (float*)(ws + sz_f12 + 2 * sz_part);

        k_sample_direct<<<NPTS / 4, 256, 0, stream>>>(kpts, ps2, feats, f12);
        k_simdist<<<NOBJ * 8 * NG / 4, 256, 0, stream>>>(f12, ps1, ps2, pmin, psum, pcnt);
        k_final<<<1, 256, 0, stream>>>(pmin, psum, pcnt, out);
    }
}

// Round 3
// 274.049 us; speedup vs baseline: 1.1088x; 1.0132x over previous
//
#include <hip/hip_runtime.h>
#include <hip/hip_bf16.h>
#include <math.h>

#define W_    384
#define H_    384
#define HW_   (384*384)
#define C_    256
#define NOBJ  16
#define NP    128
#define N2    2048
#define NF1   (NOBJ*NP)            // 2048 key points
#define NPTS  (NOBJ*NP + NOBJ*N2)  // 34816 total sampled points
#define NG    16                   // n-groups of 128 in simdist
#define NT    8                    // 16-wide n-tiles per group

typedef __attribute__((ext_vector_type(8))) short short8;
typedef __attribute__((ext_vector_type(4))) float f32x4;

__device__ __forceinline__ unsigned short f2bf(float v) {
    unsigned int u = __float_as_uint(v);
    u += 0x7fffu + ((u >> 16) & 1u);            // RNE f32->bf16
    return (unsigned short)(u >> 16);
}

// ---------------------------------------------------------------------------
// Kernel 1: transpose feats [C,H,W] f32 -> ftT [H*W, C] bf16.
// 64ch x 64pos LDS tile. Phase 1: float4 reads along p (1 KB/wave/instr).
// Phase 2: pack 8 bf16 -> uint4 store along C (1 KB/wave/instr).
// HBM-bound floor: 151 MB read + 75.5 MB write.
// ---------------------------------------------------------------------------
__global__ __launch_bounds__(256) void k_transpose(const float* __restrict__ feats,
                                                   unsigned short* __restrict__ ftT) {
    __shared__ float tile[64][65];              // +1 pad: 2-way max both phases
    int b     = blockIdx.x;
    int pbase = (b % (HW_ / 64)) * 64;
    int cbase = (b / (HW_ / 64)) * 64;
    int t     = threadIdx.x;

    int p4 = (t & 15) * 4;
    int c0 = t >> 4;                            // 0..15
    #pragma unroll
    for (int pass = 0; pass < 4; ++pass) {
        int c = c0 + pass * 16;
        float4 v = *(const float4*)(feats + (size_t)(cbase + c) * HW_ + pbase + p4);
        tile[c][p4 + 0] = v.x; tile[c][p4 + 1] = v.y;
        tile[c][p4 + 2] = v.z; tile[c][p4 + 3] = v.w;
    }
    __syncthreads();

    int c8 = (t & 7) * 8;
    int p0 = t >> 3;                            // 0..31
    #pragma unroll
    for (int pass = 0; pass < 2; ++pass) {
        int p = p0 + pass * 32;
        unsigned short u[8];
        #pragma unroll
        for (int j = 0; j < 8; ++j) u[j] = f2bf(tile[c8 + j][p]);
        uint4 pk;
        pk.x = (unsigned)u[0] | ((unsigned)u[1] << 16);
        pk.y = (unsigned)u[2] | ((unsigned)u[3] << 16);
        pk.z = (unsigned)u[4] | ((unsigned)u[5] << 16);
        pk.w = (unsigned)u[6] | ((unsigned)u[7] << 16);
        *(uint4*)(ftT + (size_t)(pbase + p) * C_ + cbase + c8) = pk;
    }
}

// ---------------------------------------------------------------------------
// Kernel 2: bilinear sample -> f12 [NPTS, C] bf16 (rows 0..2047 = f1 from
// key_points, rows 2048.. = f2 from point_set_2). Two points per wave:
// 32 lanes x 8 channels, 16 B/lane loads/stores (512 B per tap row).
// ---------------------------------------------------------------------------
__global__ __launch_bounds__(256) void k_sample(const float* __restrict__ kpts,
                                                const float* __restrict__ ps2,
                                                const unsigned short* __restrict__ ftT,
                                                unsigned short* __restrict__ f12) {
    int wave  = blockIdx.x * 4 + (threadIdx.x >> 6);
    int lane  = threadIdx.x & 63;
    int half  = lane >> 5;
    int l32   = lane & 31;
    int point = wave * 2 + half;
    int cb    = l32 * 8;

    const float* src = (point < NF1) ? (kpts + (size_t)point * 2)
                                     : (ps2 + (size_t)(point - NF1) * 2);
    // img_size == (W,H): normalization cancels; align_corners=False => -0.5
    float x  = src[0] - 0.5f;
    float y  = src[1] - 0.5f;
    float x0 = floorf(x), y0 = floorf(y);
    int ix0 = (int)x0, iy0 = (int)y0;
    float fx = x - x0, fy = y - y0;

    float a[8] = {0.f, 0.f, 0.f, 0.f, 0.f, 0.f, 0.f, 0.f};
    #pragma unroll
    for (int dy = 0; dy < 2; ++dy) {
        #pragma unroll
        for (int dx = 0; dx < 2; ++dx) {
            int ix = ix0 + dx, iy = iy0 + dy;
            float w = (dx ? fx : 1.f - fx) * (dy ? fy : 1.f - fy);
            if (ix >= 0 && ix < W_ && iy >= 0 && iy < H_) {   // half-wave uniform
                uint4 tv = *(const uint4*)(ftT + ((size_t)(iy * W_ + ix) * C_ + cb));
                a[0] += w * __uint_as_float(tv.x << 16);
                a[1] += w * __uint_as_float(tv.x & 0xffff0000u);
                a[2] += w * __uint_as_float(tv.y << 16);
                a[3] += w * __uint_as_float(tv.y & 0xffff0000u);
                a[4] += w * __uint_as_float(tv.z << 16);
                a[5] += w * __uint_as_float(tv.z & 0xffff0000u);
                a[6] += w * __uint_as_float(tv.w << 16);
                a[7] += w * __uint_as_float(tv.w & 0xffff0000u);
            }
        }
    }
    uint4 pk;
    pk.x = (unsigned)f2bf(a[0]) | ((unsigned)f2bf(a[1]) << 16);
    pk.y = (unsigned)f2bf(a[2]) | ((unsigned)f2bf(a[3]) << 16);
    pk.z = (unsigned)f2bf(a[4]) | ((unsigned)f2bf(a[5]) << 16);
    pk.w = (unsigned)f2bf(a[6]) | ((unsigned)f2bf(a[7]) << 16);
    *(uint4*)(f12 + (size_t)point * C_ + cb) = pk;
}

// Fallback sampler (no transposed copy): gathers straight from [C,H,W] f32.
__global__ __launch_bounds__(256) void k_sample_direct(const float* __restrict__ kpts,
                                                       const float* __restrict__ ps2,
                                                       const float* __restrict__ feats,
                                                       unsigned short* __restrict__ f12) {
    int point = blockIdx.x * 4 + (threadIdx.x >> 6);
    int lane  = threadIdx.x & 63;
    int cb    = lane * 4;

    const float* src = (point < NF1) ? (kpts + (size_t)point * 2)
                                     : (ps2 + (size_t)(point - NF1) * 2);
    float x  = src[0] - 0.5f, y = src[1] - 0.5f;
    float x0 = floorf(x), y0 = floorf(y);
    int ix0 = (int)x0, iy0 = (int)y0;
    float fx = x - x0, fy = y - y0;

    float acc[4] = {0.f, 0.f, 0.f, 0.f};
    #pragma unroll
    for (int dy = 0; dy < 2; ++dy) {
        #pragma unroll
        for (int dx = 0; dx < 2; ++dx) {
            int ix = ix0 + dx, iy = iy0 + dy;
            float w = (dx ? fx : 1.f - fx) * (dy ? fy : 1.f - fy);
            if (ix >= 0 && ix < W_ && iy >= 0 && iy < H_) {
                int base = iy * W_ + ix;
                #pragma unroll
                for (int u = 0; u < 4; ++u)
                    acc[u] += w * feats[(size_t)(cb + u) * HW_ + base];
            }
        }
    }
    ushort4 o;
    o.x = f2bf(acc[0]); o.y = f2bf(acc[1]); o.z = f2bf(acc[2]); o.w = f2bf(acc[3]);
    *(ushort4*)(f12 + (size_t)point * C_ + cb) = o;
}

// ---------------------------------------------------------------------------
// Kernel 3: bf16 MFMA sign-dot + masked distance stats.
// One wave per (o, 16-p tile, 128-n group). A-frags (full K=256) in 32 VGPRs;
// 8 n-tiles of 16, B-frags straight from global (L2-resident). mask =
// (dot >= 0). Partials layout: [o][p][g] for coalesced k_final reads.
// MFMA layouts per m89: C/D col=lane&15, row=(lane>>4)*4+reg;
// A/B m(n)=lane&15, k=(lane>>4)*8+j.
// ---------------------------------------------------------------------------
__global__ __launch_bounds__(256) void k_simdist(const unsigned short* __restrict__ f12,
                                                 const float* __restrict__ ps1,
                                                 const float* __restrict__ ps2,
                                                 float* __restrict__ pmin,
                                                 float* __restrict__ psum,
                                                 float* __restrict__ pcnt) {
    int wid  = blockIdx.x * 4 + (threadIdx.x >> 6);   // 0..2047
    int lane = threadIdx.x & 63;
    int ng = wid & 15;
    int pt = (wid >> 4) & 7;
    int o  = wid >> 7;
    int quad = lane >> 4, col = lane & 15;

    const short* f12s = (const short*)f12;
    const short8* aptr =
        (const short8*)(f12s + ((size_t)(o * NP + pt * 16 + col) * C_ + quad * 8));
    short8 a[8];
    #pragma unroll
    for (int kb = 0; kb < 8; ++kb) a[kb] = aptr[kb * 4];   // +32 bf16 per block

    const float2* ps1v = (const float2*)ps1;
    const float2* ps2v = (const float2*)ps2;
    float pxr[4], pyr[4];
    #pragma unroll
    for (int r = 0; r < 4; ++r) {
        float2 pc = ps1v[o * NP + pt * 16 + quad * 4 + r];
        pxr[r] = pc.x; pyr[r] = pc.y;
    }

    float mn[4] = {INFINITY, INFINITY, INFINITY, INFINITY};
    float sm[4] = {0.f, 0.f, 0.f, 0.f};
    float ct[4] = {0.f, 0.f, 0.f, 0.f};

    for (int t = 0; t < NT; ++t) {
        int nbase = ng * 128 + t * 16;
        const short8* bptr =
            (const short8*)(f12s + ((size_t)(NF1 + o * N2 + nbase + col) * C_ + quad * 8));
        f32x4 acc = {0.f, 0.f, 0.f, 0.f};
        #pragma unroll
        for (int kb = 0; kb < 8; ++kb)
            acc = __builtin_amdgcn_mfma_f32_16x16x32_bf16(a[kb], bptr[kb * 4], acc, 0, 0, 0);

        float2 nc = ps2v[o * N2 + nbase + col];   // this lane's n-column coords
        #pragma unroll
        for (int r = 0; r < 4; ++r) {
            if (acc[r] >= 0.f) {                  // sims >= 0  <=>  dot >= 0
                float dx = pxr[r] - nc.x, dy = pyr[r] - nc.y;
                float d  = sqrtf(dx * dx + dy * dy);
                mn[r] = fminf(mn[r], d); sm[r] += d; ct[r] += 1.f;
            }
        }
    }

    #pragma unroll
    for (int r = 0; r < 4; ++r) {
        #pragma unroll
        for (int off = 1; off < 16; off <<= 1) {
            mn[r] = fminf(mn[r], __shfl_xor(mn[r], off, 16));
            sm[r] += __shfl_xor(sm[r], off, 16);
            ct[r] += __shfl_xor(ct[r], off, 16);
        }
    }
    if (col == 0) {
        #pragma unroll
        for (int r = 0; r < 4; ++r) {
            int p   = pt * 16 + quad * 4 + r;
            int idx = (o * NP + p) * NG + ng;     // [o][p][g]
            pmin[idx] = mn[r]; psum[idx] = sm[r]; pcnt[idx] = ct[r];
        }
    }
}

// ---------------------------------------------------------------------------
// Kernel 4: combine group partials -> scalar loss. 1024 threads, contiguous
// 64 B reads per (o,p) pair.
// ---------------------------------------------------------------------------
__global__ __launch_bounds__(1024) void k_final(const float* __restrict__ pmin,
                                                const float* __restrict__ psum,
                                                const float* __restrict__ pcnt,
                                                float* __restrict__ out) {
    int t = threadIdx.x;
    float tot = 0.f;
    for (int pair = t; pair < NOBJ * NP; pair += 1024) {
        int base = pair * NG;
        const float4* pm = (const float4*)(pmin + base);
        const float4* ps = (const float4*)(psum + base);
        const float4* pc = (const float4*)(pcnt + base);
        float mn = INFINITY, sm = 0.f, ct = 0.f;
        #pragma unroll
        for (int g4 = 0; g4 < 4; ++g4) {
            float4 a = pm[g4], b = ps[g4], c = pc[g4];
            mn = fminf(mn, fminf(fminf(a.x, a.y), fminf(a.z, a.w)));
            sm += b.x + b.y + b.z + b.w;
            ct += c.x + c.y + c.z + c.w;
        }
        if (ct > 0.f) tot += 0.5f * (mn + sm / ct);
    }
    #pragma unroll
    for (int off = 32; off; off >>= 1) tot += __shfl_xor(tot, off, 64);
    __shared__ float wsum[16];
    if ((t & 63) == 0) wsum[t >> 6] = tot;
    __syncthreads();
    if (t < 64) {
        float v = (t < 16) ? wsum[t] : 0.f;
        #pragma unroll
        for (int off = 8; off; off >>= 1) v += __shfl_xor(v, off, 16);
        if (t == 0) out[0] = v * (1.0f / (NOBJ * NP));
    }
}

// ---------------------------------------------------------------------------
extern "C" void kernel_launch(void* const* d_in, const int* in_sizes, int n_in,
                              void* d_out, int out_size, void* d_ws, size_t ws_size,
                              hipStream_t stream) {
    const float* ps1   = (const float*)d_in[0];  // [16,128,2]
    const float* ps2   = (const float*)d_in[1];  // [16,2048,2]
    const float* feats = (const float*)d_in[2];  // [1,256,384,384]
    const float* kpts  = (const float*)d_in[3];  // [2048,2]
    float* out = (float*)d_out;

    const size_t sz_ftT  = (size_t)HW_ * C_ * sizeof(unsigned short);   // 75,497,472
    const size_t sz_f12  = (size_t)NPTS * C_ * sizeof(unsigned short);  // 17,825,792
    const size_t sz_part = (size_t)NOBJ * NP * NG * sizeof(float);      //    131,072

    char* ws = (char*)d_ws;
    if (ws_size >= sz_ftT + sz_f12 + 3 * sz_part) {
        unsigned short* ftT = (unsigned short*)ws;
        unsigned short* f12 = (unsigned short*)(ws + sz_ftT);
        float* pmin = (float*)(ws + sz_ftT + sz_f12);
        float* psum = (float*)(ws + sz_ftT + sz_f12 + sz_part);
        float* pcnt = (float*)(ws + sz_ftT + sz_f12 + 2 * sz_part);

        k_transpose<<<(HW_ / 64) * (C_ / 64), 256, 0, stream>>>(feats, ftT);
        k_sample<<<NPTS / 8, 256, 0, stream>>>(kpts, ps2, ftT, f12);
        k_simdist<<<NOBJ * 8 * NG / 4, 256, 0, stream>>>(f12, ps1, ps2, pmin, psum, pcnt);
        k_final<<<1, 1024, 0, stream>>>(pmin, psum, pcnt, out);
    } else {
        // Fallback: no transposed feature copy (uncoalesced gathers, but correct).
        unsigned short* f12 = (unsigned short*)ws;
        float* pmin = (float*)(ws + sz_f12);
        float* psum = (float*)(ws + sz_f12 + sz_part);
        float* pcnt = (float*)(ws + sz_f12 + 2 * sz_part);

        k_sample_direct<<<NPTS / 4, 256, 0, stream>>>(kpts, ps2, feats, f12);
        k_simdist<<<NOBJ * 8 * NG / 4, 256, 0, stream>>>(f12, ps1, ps2, pmin, psum, pcnt);
        k_final<<<1, 1024, 0, stream>>>(pmin, psum, pcnt, out);
    }
}